// Round 8
// baseline (50.217 us; speedup 1.0000x reference)
//
#include <hip/hip_runtime.h>

#define NT 24
#define SQ 1024
#define NB 1024
#define NSEG 64
#define LSEG 16
#define TS 8

typedef float f32x16 __attribute__((ext_vector_type(16)));
typedef short bf16x8 __attribute__((ext_vector_type(8)));
typedef unsigned int uint2v __attribute__((ext_vector_type(2)));
typedef unsigned long long u64;

__device__ __forceinline__ unsigned short bfrnd(float x) {
    unsigned u = __float_as_uint(x);
    return (unsigned short)((u + 0x7fffu + ((u >> 16) & 1u)) >> 16);
}
__device__ __forceinline__ unsigned cvtpk(float lo, float hi) {
    unsigned r;
    asm("v_cvt_pk_bf16_f32 %0, %1, %2" : "=v"(r) : "v"(lo), "v"(hi));
    return r;
}
__device__ __forceinline__ float bflo(unsigned p) { return __uint_as_float(p << 16); }
__device__ __forceinline__ float bfhi(unsigned p) { return __uint_as_float(p & 0xffff0000u); }

// Issue one 8-step tile's global loads (coalesced 128B runs) into registers.
__device__ __forceinline__ void stage_issue(
    float4 (&pre)[24], const float* __restrict__ fbase, int t0, int sg, int sf)
{
#pragma unroll
    for (int q = 0; q < 24; ++q) {
        int sb = 8 * (q & 3) + sg;       // batch within group
        int f4 = 8 * (q >> 2) + sf;      // float4 index within 8x24 tile (0..47)
        pre[q] = *(const float4*)(fbase + (size_t)sb * SQ * NT + (size_t)t0 * NT + f4 * 4);
    }
}

// Convert to bf16 and write LDS tile X[k][j4][sb] (u64 = 4 bf16).
__device__ __forceinline__ void stage_write(
    const float4 (&pre)[24], u64* __restrict__ ldsX, int sg, int sf)
{
#pragma unroll
    for (int q = 0; q < 24; ++q) {
        int sb = 8 * (q & 3) + sg;
        int f4 = 8 * (q >> 2) + sf;
        int tl = f4 / 6, j4 = f4 % 6;
        unsigned lo = cvtpk(pre[q].x, pre[q].y);
        unsigned hi2 = cvtpk(pre[q].z, pre[q].w);
        ldsX[(tl * 6 + j4) * 32 + sb] = ((u64)hi2 << 32) | lo;
    }
}

// MODE: 0 normal, 1 first tile of sequence (t=0 init), 3 warmup (no numerator)
template<int MODE>
__device__ __forceinline__ void tile_compute(
    u64 tg64, unsigned pbyte, bf16x8 A1, bf16x8 A2,
    const u64* __restrict__ ldsX, const float* __restrict__ ldsT,
    const float* __restrict__ ldsS,
    int hi, int c, float (&w)[12], float& lz2, float& numAcc, int& cnt)
{
    const unsigned short* lds16 = (const unsigned short*)ldsX;
    // ---- numerator: lane (hi,c) owns steps k = hi*4 + i of batch c ----
    if (MODE != 3) {
#pragma unroll
        for (int i = 0; i < 4; ++i) {
            int k = hi * 4 + i;
            int by = (int)(tg64 >> (8 * k)) & 255;
            int tg = by & 31;
            int m = by >> 7;
            int pv = (k == 0) ? (int)(pbyte & 31) : ((int)(tg64 >> (8 * k - 8)) & 31);
            float emv = __uint_as_float(
                (unsigned)lds16[((k * 6 + (tg >> 2)) * 32 + c) * 4 + (tg & 3)] << 16);
            float contrib;
            if (MODE == 1 && hi == 0 && i == 0)
                contrib = ldsS[tg] + emv;            // t=0: start+em0, unmasked
            else
                contrib = m ? (ldsT[pv * NT + tg] + emv) : 0.0f;
            numAcc += contrib;
            cnt += m;
        }
    }
    // ---- w recurrence: 8 steps from LDS, state in registers ----
#pragma unroll
    for (int k = 0; k < TS; ++k) {
        const u64* xk = ldsX + k * 6 * 32;
        u64 d0 = xk[(hi + 0) * 32 + c];
        u64 d1 = xk[(hi + 2) * 32 + c];
        u64 d2 = xk[(hi + 4) * 32 + c];
        unsigned l0 = (unsigned)d0, h0 = (unsigned)(d0 >> 32);
        unsigned l1 = (unsigned)d1, h1 = (unsigned)(d1 >> 32);
        unsigned l2 = (unsigned)d2, h2 = (unsigned)(d2 >> 32);
        float ee[12] = {bflo(l0), bfhi(l0), bflo(h0), bfhi(h0),
                        bflo(l1), bfhi(l1), bflo(h1), bfhi(h1),
                        bflo(l2), bfhi(l2), bflo(h2), bfhi(h2)};
        if (MODE == 1 && k == 0) {
#pragma unroll
            for (int r = 0; r < 12; ++r) {
                int R = (r & 3) + 8 * (r >> 2) + 4 * hi;
                w[r] = __expf(ldsS[R] + ee[r]);
            }
            continue;
        }
        int m = (int)(tg64 >> (8 * k + 7)) & 1;
        // B = bf16(W) in MFMA-B layout via cvt_pk + permlane32_swap
        unsigned aw = cvtpk(w[0], w[1]);
        unsigned bw = cvtpk(w[2], w[3]);
        unsigned cw = cvtpk(w[4], w[5]);
        unsigned dw = cvtpk(w[6], w[7]);
        unsigned ew = cvtpk(w[8], w[9]);
        unsigned fw = cvtpk(w[10], w[11]);
        uint2v s1 = __builtin_amdgcn_permlane32_swap(aw, cw, false, false);
        uint2v s2 = __builtin_amdgcn_permlane32_swap(bw, dw, false, false);
        uint2v s3 = __builtin_amdgcn_permlane32_swap(ew, 0u, false, false);
        uint2v s4 = __builtin_amdgcn_permlane32_swap(fw, 0u, false, false);
        union { unsigned u[4]; bf16x8 v; } B1, B2;
        B1.u[0] = s1[0]; B1.u[1] = s2[0]; B1.u[2] = s1[1]; B1.u[3] = s2[1];
        B2.u[0] = s3[0]; B2.u[1] = s4[0]; B2.u[2] = s3[1]; B2.u[3] = s4[1];
        f32x16 acc = {};
        acc = __builtin_amdgcn_mfma_f32_32x32x16_bf16(A1, B1.v, acc, 0, 0, 0);
        acc = __builtin_amdgcn_mfma_f32_32x32x16_bf16(A2, B2.v, acc, 0, 0, 0);
#pragma unroll
        for (int r = 0; r < 12; ++r) {
            float q = acc[r] * __expf(ee[r]);
            w[r] = m ? q : w[r];
        }
        if ((k & 3) == 3) {   // renormalize every 4 steps (invariant exact)
            float zh = ((w[0] + w[1]) + (w[2] + w[3])) +
                       ((w[4] + w[5]) + (w[6] + w[7])) +
                       ((w[8] + w[9]) + (w[10] + w[11]));
            float zt = zh + __shfl_xor(zh, 32);
            float rz = __builtin_amdgcn_rcpf(zt);
            lz2 += __log2f(zt);
#pragma unroll
            for (int r = 0; r < 12; ++r) w[r] *= rz;
        }
    }
}

// Pack tag|mask<<7 bytes into transposed u64 octets: tagT[t/8][b].
extern "C" __global__ void __launch_bounds__(128)
crf_pack(const int* __restrict__ target, const int* __restrict__ maskp,
         u64* __restrict__ tagT)
{
    const int b = blockIdx.x;
    const int oct = threadIdx.x;      // 0..127
    const int* tb = target + (size_t)b * SQ + oct * 8;
    const int* mb = maskp + (size_t)b * SQ + oct * 8;
    int4 t0 = *(const int4*)tb, t1 = *(const int4*)(tb + 4);
    int4 m0 = *(const int4*)mb, m1 = *(const int4*)(mb + 4);
    int tg[8] = {t0.x, t0.y, t0.z, t0.w, t1.x, t1.y, t1.z, t1.w};
    int mk[8] = {m0.x, m0.y, m0.z, m0.w, m1.x, m1.y, m1.z, m1.w};
    u64 v = 0;
#pragma unroll
    for (int i = 0; i < 8; ++i)
        v |= (u64)((tg[i] & 31) | (mk[i] ? 128 : 0)) << (8 * i);
    tagT[(size_t)oct * NB + b] = v;
}

extern "C" __global__ void __launch_bounds__(64, 2)
crf_fwd(const float* __restrict__ feat,
        const float* __restrict__ startT, const float* __restrict__ endT,
        const float* __restrict__ trans,
        const u64* __restrict__ tagT,
        float* __restrict__ dP, float* __restrict__ nP, int* __restrict__ cP)
{
    __shared__ float ldsT[NT * NT];
    __shared__ float ldsS[NT];
    __shared__ float ldsE[NT];
    __shared__ __align__(16) u64 ldsX[TS * 6 * 32];   // 12,288 B bf16 em tile

    const int tid = threadIdx.x;
    const int hi = tid >> 5;
    const int c = tid & 31;
    const int sg = tid >> 3;          // staging: batch lane group (0..7)
    const int sf = tid & 7;           // staging: f4 within 128B run
    const int grp = blockIdx.x;       // 2048 groups = (bg, p)
    const int bg = grp >> 6;          // NSEG = 64
    const int p = grp & (NSEG - 1);
    const int b = bg * 32 + c;

    for (int i = tid; i < NT * NT; i += 64) ldsT[i] = trans[i];
    if (tid < NT) { ldsS[tid] = startT[tid]; ldsE[tid] = endT[tid]; }
    __syncthreads();

    // A = exp(trans^T) constant frags: A[row=c][k] = exp(trans[k][c]), pad 0
    union { unsigned short s[8]; bf16x8 v; } A1u, A2u;
#pragma unroll
    for (int j = 0; j < 8; ++j) {
        int k1 = 8 * hi + j;
        float v1 = (c < NT && k1 < NT) ? __expf(ldsT[k1 * NT + c]) : 0.0f;
        A1u.s[j] = bfrnd(v1);
        int k2 = 16 + 8 * hi + j;
        float v2 = (c < NT && k2 < NT) ? __expf(ldsT[k2 * NT + c]) : 0.0f;
        A2u.s[j] = bfrnd(v2);
    }

    const float* fbase = feat + (size_t)bg * 32 * SQ * NT;

    float w[12];
#pragma unroll
    for (int r = 0; r < 12; ++r) w[r] = 1.0f;
    float lz2 = 0.0f, sub2 = 0.0f, numAcc = 0.0f;
    int cnt = 0;
    const int a = p * LSEG;

    float4 pre[24];
    u64 tg0 = tagT[(size_t)(a >> 3) * NB + b];
    u64 tg1 = tagT[(size_t)((a + 8) >> 3) * NB + b];

    if (p > 0) {
        u64 tgW = tagT[(size_t)((a - 8) >> 3) * NB + b];
        stage_issue(pre, fbase, a - 8, sg, sf);
        stage_write(pre, ldsX, sg, sf);
        __syncthreads();
        stage_issue(pre, fbase, a, sg, sf);            // in flight under warmup
        tile_compute<3>(tgW, 0, A1u.v, A2u.v, ldsX, ldsT, ldsS,
                        hi, c, w, lz2, numAcc, cnt);
        // capture segment-start scale (state = w_{a-1}); cancels warmup init
        float zh = ((w[0] + w[1]) + (w[2] + w[3])) + ((w[4] + w[5]) + (w[6] + w[7])) +
                   ((w[8] + w[9]) + (w[10] + w[11]));
        float zt = zh + __shfl_xor(zh, 32);
        sub2 = lz2 + __log2f(zt);
        stage_write(pre, ldsX, sg, sf);
        __syncthreads();
        stage_issue(pre, fbase, a + 8, sg, sf);        // in flight under M0
        tile_compute<0>(tg0, (unsigned)(tgW >> 56), A1u.v, A2u.v, ldsX, ldsT, ldsS,
                        hi, c, w, lz2, numAcc, cnt);
        stage_write(pre, ldsX, sg, sf);
        __syncthreads();
        tile_compute<0>(tg1, (unsigned)(tg0 >> 56), A1u.v, A2u.v, ldsX, ldsT, ldsS,
                        hi, c, w, lz2, numAcc, cnt);
    } else {
        stage_issue(pre, fbase, 0, sg, sf);
        stage_write(pre, ldsX, sg, sf);
        __syncthreads();
        stage_issue(pre, fbase, 8, sg, sf);
        tile_compute<1>(tg0, 0, A1u.v, A2u.v, ldsX, ldsT, ldsS,
                        hi, c, w, lz2, numAcc, cnt);
        stage_write(pre, ldsX, sg, sf);
        __syncthreads();
        tile_compute<0>(tg1, (unsigned)(tg0 >> 56), A1u.v, A2u.v, ldsX, ldsT, ldsS,
                        hi, c, w, lz2, numAcc, cnt);
    }

    // ---- segment epilogue ----
    float ze = 0.0f;
#pragma unroll
    for (int r = 0; r < 12; ++r) {
        int R = (r & 3) + 8 * (r >> 2) + 4 * hi;
        float wv = w[r];
        if (p == NSEG - 1) wv *= __expf(ldsE[R]);
        ze += wv;
    }
    float zt = ze + __shfl_xor(ze, 32);
    float res = (lz2 + __log2f(zt) - sub2) * 0.6931471805599453f;
    float ntot = numAcc + __shfl_xor(numAcc, 32);
    int ctot = cnt + __shfl_xor(cnt, 32);
    if (hi == 0) {
        dP[p * NB + b] = res;
        nP[p * NB + b] = ntot;
        cP[p * NB + b] = ctot;
    }
}

extern "C" __global__ void __launch_bounds__(64)
crf_combine(const float* __restrict__ dP, const float* __restrict__ nP,
            const int* __restrict__ cP, const int* __restrict__ target,
            const float* __restrict__ endT, float* __restrict__ bpart)
{
    const int b = blockIdx.x * 64 + threadIdx.x;
    float den = 0.f, num = 0.f;
    int cnt = 0;
#pragma unroll 8
    for (int p = 0; p < NSEG; ++p) {
        den += dP[p * NB + b];
        num += nP[p * NB + b];
        cnt += cP[p * NB + b];
    }
    int lastTag = target[(size_t)b * SQ + (cnt - 1)];
    float llh = (num + endT[lastTag]) - den;
#pragma unroll
    for (int m = 1; m < 64; m <<= 1) llh += __shfl_xor(llh, m, 64);
    if (threadIdx.x == 0) bpart[blockIdx.x] = llh;
}

extern "C" __global__ void __launch_bounds__(64)
crf_final(const float* __restrict__ bpart, float* __restrict__ out)
{
    float s = (threadIdx.x < NB / 64) ? bpart[threadIdx.x] : 0.0f;
#pragma unroll
    for (int m = 1; m < 64; m <<= 1) s += __shfl_xor(s, m, 64);
    if (threadIdx.x == 0) out[0] = -s * (1.0f / NB);
}

extern "C" void kernel_launch(void* const* d_in, const int* in_sizes, int n_in,
                              void* d_out, int out_size, void* d_ws, size_t ws_size,
                              hipStream_t stream)
{
    const float* feat   = (const float*)d_in[0];
    const int*   maskp  = (const int*)d_in[1];
    const int*   target = (const int*)d_in[2];
    const float* startT = (const float*)d_in[3];
    const float* endT   = (const float*)d_in[4];
    const float* trans  = (const float*)d_in[5];

    u64*   tagT = (u64*)d_ws;                        // [SQ/8 * NB] = 1 MB
    float* dP = (float*)(tagT + (SQ / 8) * NB);      // [NSEG*NB]
    float* nP = dP + NSEG * NB;                      // [NSEG*NB]
    int*   cP = (int*)(nP + NSEG * NB);              // [NSEG*NB]
    float* bpart = (float*)(cP + NSEG * NB);         // [NB/64]

    crf_pack<<<NB, 128, 0, stream>>>(target, maskp, tagT);
    crf_fwd<<<(NB / 32) * NSEG, 64, 0, stream>>>(feat, startT, endT, trans, tagT,
                                                 dP, nP, cP);
    crf_combine<<<NB / 64, 64, 0, stream>>>(dP, nP, cP, target, endT, bpart);
    crf_final<<<1, 64, 0, stream>>>(bpart, (float*)d_out);
}

// Round 9
// 48.155 us; speedup vs baseline: 1.0428x; 1.0428x over previous
//
#include <hip/hip_runtime.h>

#define NT 24
#define SQ 1024
#define NB 1024
#define NSEG 64
#define LSEG 16
#define TS 8

typedef float f32x16 __attribute__((ext_vector_type(16)));
typedef short bf16x8 __attribute__((ext_vector_type(8)));
typedef unsigned int uint2v __attribute__((ext_vector_type(2)));
typedef unsigned long long u64;

__device__ __forceinline__ unsigned short bfrnd(float x) {
    unsigned u = __float_as_uint(x);
    return (unsigned short)((u + 0x7fffu + ((u >> 16) & 1u)) >> 16);
}
__device__ __forceinline__ unsigned cvtpk(float lo, float hi) {
    unsigned r;
    asm("v_cvt_pk_bf16_f32 %0, %1, %2" : "=v"(r) : "v"(lo), "v"(hi));
    return r;
}
__device__ __forceinline__ float bflo(unsigned p) { return __uint_as_float(p << 16); }
__device__ __forceinline__ float bfhi(unsigned p) { return __uint_as_float(p & 0xffff0000u); }

// Issue one 8-step tile's global loads (coalesced 128B runs) into registers.
__device__ __forceinline__ void stage_issue(
    float4 (&pre)[24], const float* __restrict__ fbase, int t0, int sg, int sf)
{
#pragma unroll
    for (int q = 0; q < 24; ++q) {
        int sb = 8 * (q & 3) + sg;       // batch within group
        int f4 = 8 * (q >> 2) + sf;      // float4 index within 8x24 tile (0..47)
        pre[q] = *(const float4*)(fbase + (size_t)sb * SQ * NT + (size_t)t0 * NT + f4 * 4);
    }
}

// Convert to bf16 and write LDS tile X[row=f4][sb^, row&7] (u64 = 4 bf16).
// XOR swizzle on sb spreads the 8 same-sb lanes of a write across 8 banks.
__device__ __forceinline__ void stage_write(
    const float4 (&pre)[24], u64* __restrict__ ldsX, int sg, int sf)
{
#pragma unroll
    for (int q = 0; q < 24; ++q) {
        int sb = 8 * (q & 3) + sg;
        int f4 = 8 * (q >> 2) + sf;      // == row index (0..47)
        unsigned lo = cvtpk(pre[q].x, pre[q].y);
        unsigned hi2 = cvtpk(pre[q].z, pre[q].w);
        ldsX[f4 * 32 + (sb ^ (f4 & 7))] = ((u64)hi2 << 32) | lo;
    }
}

// MODE: 0 normal, 1 first tile of sequence (t=0 init), 3 warmup (no numerator)
template<int MODE>
__device__ __forceinline__ void tile_compute(
    u64 tg64, unsigned pbyte, bf16x8 A1, bf16x8 A2,
    const u64* __restrict__ ldsX, const float* __restrict__ ldsT,
    const float* __restrict__ ldsS,
    int hi, int c, float (&w)[12], float& lz2, float& numAcc, int& cnt)
{
    const unsigned short* lds16 = (const unsigned short*)ldsX;
    // ---- numerator: lane (hi,c) owns steps k = hi*4 + i of batch c ----
    if (MODE != 3) {
#pragma unroll
        for (int i = 0; i < 4; ++i) {
            int k = hi * 4 + i;
            int by = (int)(tg64 >> (8 * k)) & 255;
            int tg = by & 31;
            int m = by >> 7;
            int pv = (k == 0) ? (int)(pbyte & 31) : ((int)(tg64 >> (8 * k - 8)) & 31);
            int row = k * 6 + (tg >> 2);
            float emv = __uint_as_float(
                (unsigned)lds16[(row * 32 + (c ^ (row & 7))) * 4 + (tg & 3)] << 16);
            float contrib;
            if (MODE == 1 && hi == 0 && i == 0)
                contrib = ldsS[tg] + emv;            // t=0: start+em0, unmasked
            else
                contrib = m ? (ldsT[pv * NT + tg] + emv) : 0.0f;
            numAcc += contrib;
            cnt += m;
        }
    }
    // ---- w recurrence: 8 steps from LDS, state in registers ----
#pragma unroll
    for (int k = 0; k < TS; ++k) {
        int r0 = k * 6 + hi;
        int r1 = r0 + 2;
        int r2 = r0 + 4;
        u64 d0 = ldsX[r0 * 32 + (c ^ (r0 & 7))];
        u64 d1 = ldsX[r1 * 32 + (c ^ (r1 & 7))];
        u64 d2 = ldsX[r2 * 32 + (c ^ (r2 & 7))];
        unsigned l0 = (unsigned)d0, h0 = (unsigned)(d0 >> 32);
        unsigned l1 = (unsigned)d1, h1 = (unsigned)(d1 >> 32);
        unsigned l2 = (unsigned)d2, h2 = (unsigned)(d2 >> 32);
        float ee[12] = {bflo(l0), bfhi(l0), bflo(h0), bfhi(h0),
                        bflo(l1), bfhi(l1), bflo(h1), bfhi(h1),
                        bflo(l2), bfhi(l2), bflo(h2), bfhi(h2)};
        if (MODE == 1 && k == 0) {
#pragma unroll
            for (int r = 0; r < 12; ++r) {
                int R = (r & 3) + 8 * (r >> 2) + 4 * hi;
                w[r] = __expf(ldsS[R] + ee[r]);
            }
            continue;
        }
        int m = (int)(tg64 >> (8 * k + 7)) & 1;
        // B = bf16(W) in MFMA-B layout via cvt_pk + permlane32_swap
        unsigned aw = cvtpk(w[0], w[1]);
        unsigned bw = cvtpk(w[2], w[3]);
        unsigned cw = cvtpk(w[4], w[5]);
        unsigned dw = cvtpk(w[6], w[7]);
        unsigned ew = cvtpk(w[8], w[9]);
        unsigned fw = cvtpk(w[10], w[11]);
        uint2v s1 = __builtin_amdgcn_permlane32_swap(aw, cw, false, false);
        uint2v s2 = __builtin_amdgcn_permlane32_swap(bw, dw, false, false);
        uint2v s3 = __builtin_amdgcn_permlane32_swap(ew, 0u, false, false);
        uint2v s4 = __builtin_amdgcn_permlane32_swap(fw, 0u, false, false);
        union { unsigned u[4]; bf16x8 v; } B1, B2;
        B1.u[0] = s1[0]; B1.u[1] = s2[0]; B1.u[2] = s1[1]; B1.u[3] = s2[1];
        B2.u[0] = s3[0]; B2.u[1] = s4[0]; B2.u[2] = s3[1]; B2.u[3] = s4[1];
        // independent MFMAs (no serial acc dependency), summed on VALU
        f32x16 z16 = {};
        f32x16 acc1 = __builtin_amdgcn_mfma_f32_32x32x16_bf16(A1, B1.v, z16, 0, 0, 0);
        f32x16 acc2 = __builtin_amdgcn_mfma_f32_32x32x16_bf16(A2, B2.v, z16, 0, 0, 0);
#pragma unroll
        for (int r = 0; r < 12; ++r) {
            float q = (acc1[r] + acc2[r]) * __expf(ee[r]);
            w[r] = m ? q : w[r];
        }
        if ((k & 3) == 3) {   // renormalize every 4 steps (invariant exact)
            float zh = ((w[0] + w[1]) + (w[2] + w[3])) +
                       ((w[4] + w[5]) + (w[6] + w[7])) +
                       ((w[8] + w[9]) + (w[10] + w[11]));
            float zt = zh + __shfl_xor(zh, 32);
            float rz = __builtin_amdgcn_rcpf(zt);
            lz2 += __log2f(zt);
#pragma unroll
            for (int r = 0; r < 12; ++r) w[r] *= rz;
        }
    }
}

// Pack tag|mask<<7 bytes into transposed u64 octets: tagT[t/8][b].
extern "C" __global__ void __launch_bounds__(128)
crf_pack(const int* __restrict__ target, const int* __restrict__ maskp,
         u64* __restrict__ tagT)
{
    const int b = blockIdx.x;
    const int oct = threadIdx.x;      // 0..127
    const int* tb = target + (size_t)b * SQ + oct * 8;
    const int* mb = maskp + (size_t)b * SQ + oct * 8;
    int4 t0 = *(const int4*)tb, t1 = *(const int4*)(tb + 4);
    int4 m0 = *(const int4*)mb, m1 = *(const int4*)(mb + 4);
    int tg[8] = {t0.x, t0.y, t0.z, t0.w, t1.x, t1.y, t1.z, t1.w};
    int mk[8] = {m0.x, m0.y, m0.z, m0.w, m1.x, m1.y, m1.z, m1.w};
    u64 v = 0;
#pragma unroll
    for (int i = 0; i < 8; ++i)
        v |= (u64)((tg[i] & 31) | (mk[i] ? 128 : 0)) << (8 * i);
    tagT[(size_t)oct * NB + b] = v;
}

extern "C" __global__ void __launch_bounds__(64, 2)
crf_fwd(const float* __restrict__ feat,
        const float* __restrict__ startT, const float* __restrict__ endT,
        const float* __restrict__ trans,
        const u64* __restrict__ tagT,
        float* __restrict__ dP, float* __restrict__ nP, int* __restrict__ cP)
{
    __shared__ float ldsT[NT * NT];
    __shared__ float ldsS[NT];
    __shared__ float ldsE[NT];
    __shared__ __align__(16) u64 ldsX[TS * 6 * 32];   // 12,288 B bf16 em tile

    const int tid = threadIdx.x;
    const int hi = tid >> 5;
    const int c = tid & 31;
    const int sg = tid >> 3;          // staging: batch lane group (0..7)
    const int sf = tid & 7;           // staging: f4 within 128B run
    // XCD-slab swizzle: all 64 segments of one batch-group (3 MB feature slab,
    // fits one XCD's 4 MB L2) land on the same XCD in consecutive order.
    // Bijective for any actual dispatch mapping -> correctness-safe.
    const int bid = blockIdx.x;       // 2048 blocks
    const int xcd = bid & 7;
    const int idx = bid >> 3;         // 0..255 per XCD slot
    const int bg = (idx >> 6) * 8 + xcd;   // 0..31
    const int p = idx & 63;                // 0..63
    const int b = bg * 32 + c;

    for (int i = tid; i < NT * NT; i += 64) ldsT[i] = trans[i];
    if (tid < NT) { ldsS[tid] = startT[tid]; ldsE[tid] = endT[tid]; }
    __syncthreads();

    // A = exp(trans^T) constant frags: A[row=c][k] = exp(trans[k][c]), pad 0
    union { unsigned short s[8]; bf16x8 v; } A1u, A2u;
#pragma unroll
    for (int j = 0; j < 8; ++j) {
        int k1 = 8 * hi + j;
        float v1 = (c < NT && k1 < NT) ? __expf(ldsT[k1 * NT + c]) : 0.0f;
        A1u.s[j] = bfrnd(v1);
        int k2 = 16 + 8 * hi + j;
        float v2 = (c < NT && k2 < NT) ? __expf(ldsT[k2 * NT + c]) : 0.0f;
        A2u.s[j] = bfrnd(v2);
    }

    const float* fbase = feat + (size_t)bg * 32 * SQ * NT;

    float w[12];
#pragma unroll
    for (int r = 0; r < 12; ++r) w[r] = 1.0f;
    float lz2 = 0.0f, sub2 = 0.0f, numAcc = 0.0f;
    int cnt = 0;
    const int a = p * LSEG;

    float4 pre[24];
    u64 tg0 = tagT[(size_t)(a >> 3) * NB + b];
    u64 tg1 = tagT[(size_t)((a + 8) >> 3) * NB + b];

    if (p > 0) {
        u64 tgW = tagT[(size_t)((a - 8) >> 3) * NB + b];
        stage_issue(pre, fbase, a - 8, sg, sf);
        stage_write(pre, ldsX, sg, sf);
        __syncthreads();
        stage_issue(pre, fbase, a, sg, sf);            // in flight under warmup
        tile_compute<3>(tgW, 0, A1u.v, A2u.v, ldsX, ldsT, ldsS,
                        hi, c, w, lz2, numAcc, cnt);
        // capture segment-start scale (state = w_{a-1}); cancels warmup init
        float zh = ((w[0] + w[1]) + (w[2] + w[3])) + ((w[4] + w[5]) + (w[6] + w[7])) +
                   ((w[8] + w[9]) + (w[10] + w[11]));
        float zt = zh + __shfl_xor(zh, 32);
        sub2 = lz2 + __log2f(zt);
        stage_write(pre, ldsX, sg, sf);
        __syncthreads();
        stage_issue(pre, fbase, a + 8, sg, sf);        // in flight under M0
        tile_compute<0>(tg0, (unsigned)(tgW >> 56), A1u.v, A2u.v, ldsX, ldsT, ldsS,
                        hi, c, w, lz2, numAcc, cnt);
        stage_write(pre, ldsX, sg, sf);
        __syncthreads();
        tile_compute<0>(tg1, (unsigned)(tg0 >> 56), A1u.v, A2u.v, ldsX, ldsT, ldsS,
                        hi, c, w, lz2, numAcc, cnt);
    } else {
        stage_issue(pre, fbase, 0, sg, sf);
        stage_write(pre, ldsX, sg, sf);
        __syncthreads();
        stage_issue(pre, fbase, 8, sg, sf);
        tile_compute<1>(tg0, 0, A1u.v, A2u.v, ldsX, ldsT, ldsS,
                        hi, c, w, lz2, numAcc, cnt);
        stage_write(pre, ldsX, sg, sf);
        __syncthreads();
        tile_compute<0>(tg1, (unsigned)(tg0 >> 56), A1u.v, A2u.v, ldsX, ldsT, ldsS,
                        hi, c, w, lz2, numAcc, cnt);
    }

    // ---- segment epilogue ----
    float ze = 0.0f;
#pragma unroll
    for (int r = 0; r < 12; ++r) {
        int R = (r & 3) + 8 * (r >> 2) + 4 * hi;
        float wv = w[r];
        if (p == NSEG - 1) wv *= __expf(ldsE[R]);
        ze += wv;
    }
    float zt = ze + __shfl_xor(ze, 32);
    float res = (lz2 + __log2f(zt) - sub2) * 0.6931471805599453f;
    float ntot = numAcc + __shfl_xor(numAcc, 32);
    int ctot = cnt + __shfl_xor(cnt, 32);
    if (hi == 0) {
        dP[p * NB + b] = res;
        nP[p * NB + b] = ntot;
        cP[p * NB + b] = ctot;
    }
}

extern "C" __global__ void __launch_bounds__(64)
crf_combine(const float* __restrict__ dP, const float* __restrict__ nP,
            const int* __restrict__ cP, const int* __restrict__ target,
            const float* __restrict__ endT, float* __restrict__ bpart)
{
    const int b = blockIdx.x * 64 + threadIdx.x;
    float den = 0.f, num = 0.f;
    int cnt = 0;
#pragma unroll 8
    for (int p = 0; p < NSEG; ++p) {
        den += dP[p * NB + b];
        num += nP[p * NB + b];
        cnt += cP[p * NB + b];
    }
    int lastTag = target[(size_t)b * SQ + (cnt - 1)];
    float llh = (num + endT[lastTag]) - den;
#pragma unroll
    for (int m = 1; m < 64; m <<= 1) llh += __shfl_xor(llh, m, 64);
    if (threadIdx.x == 0) bpart[blockIdx.x] = llh;
}

extern "C" __global__ void __launch_bounds__(64)
crf_final(const float* __restrict__ bpart, float* __restrict__ out)
{
    float s = (threadIdx.x < NB / 64) ? bpart[threadIdx.x] : 0.0f;
#pragma unroll
    for (int m = 1; m < 64; m <<= 1) s += __shfl_xor(s, m, 64);
    if (threadIdx.x == 0) out[0] = -s * (1.0f / NB);
}

extern "C" void kernel_launch(void* const* d_in, const int* in_sizes, int n_in,
                              void* d_out, int out_size, void* d_ws, size_t ws_size,
                              hipStream_t stream)
{
    const float* feat   = (const float*)d_in[0];
    const int*   maskp  = (const int*)d_in[1];
    const int*   target = (const int*)d_in[2];
    const float* startT = (const float*)d_in[3];
    const float* endT   = (const float*)d_in[4];
    const float* trans  = (const float*)d_in[5];

    u64*   tagT = (u64*)d_ws;                        // [SQ/8 * NB] = 1 MB
    float* dP = (float*)(tagT + (SQ / 8) * NB);      // [NSEG*NB]
    float* nP = dP + NSEG * NB;                      // [NSEG*NB]
    int*   cP = (int*)(nP + NSEG * NB);              // [NSEG*NB]
    float* bpart = (float*)(cP + NSEG * NB);         // [NB/64]

    crf_pack<<<NB, 128, 0, stream>>>(target, maskp, tagT);
    crf_fwd<<<(NB / 32) * NSEG, 64, 0, stream>>>(feat, startT, endT, trans, tagT,
                                                 dP, nP, cP);
    crf_combine<<<NB / 64, 64, 0, stream>>>(dP, nP, cP, target, endT, bpart);
    crf_final<<<1, 64, 0, stream>>>(bpart, (float*)d_out);
}